// Round 5
// baseline (240.542 us; speedup 1.0000x reference)
//
#include <hip/hip_runtime.h>
#include <hip/hip_bf16.h>

typedef __attribute__((ext_vector_type(8))) short short8;   // 8 bf16 (A/B frag)
typedef __attribute__((ext_vector_type(4))) short bf16x4;   // 4 bf16 (8B store)
typedef __attribute__((ext_vector_type(4))) float f32x4;    // 4 fp32 (C/D frag)

// b=32, C=128, n=4096, heads=4, dh=32. All I/O fp32; MFMA bf16, fp32 accum.
// K1: round-2's proven 68us structure (full-width swizzled kbuf/vbuf, 3-section
// loop, xr prefetch, launch_bounds(256,2)), re-gridded to 1024 = 32 b * 32 groups
// x 2 tiles (LDS 50 KB allows 3 blocks/CU; grid 512 capped residency at 2).
// K3: obuf restage deleted (direct 64B-segment stores), LDS 16 KB, 1 barrier.
//
// ws (float units):
//   Sp  bf16 frag-major [32][32][4096] @ 0            (exactly fills 2097152 fl)
//   Zp  bf16 [32][32][128]  @ 2097152
//   Mtf bf16 frag-major     @ 2162688
//   Wf  bf16 frag-major     @ 2424832
//   gs  [128]               @ 2449408
//   qbf bf16 frag-major     @ 2449536

__device__ __forceinline__ unsigned short f2bf(float f) {  // RNE, finite inputs
  unsigned u = __float_as_uint(f);
  u += 0x7fff + ((u >> 16) & 1);
  return (unsigned short)(u >> 16);
}
__device__ __forceinline__ float bf2f(unsigned short s) {
  return __uint_as_float(((unsigned)s) << 16);
}

// ---------------- K0: pack Wf frag-major, gs ----------------
__global__ void k0_init(const float* __restrict__ wqkv, const float* __restrict__ g,
                        float* __restrict__ ws) {
  int tid = blockIdx.x * blockDim.x + threadIdx.x;
  int stride = gridDim.x * blockDim.x;
  unsigned short* Wf = (unsigned short*)(ws + 2424832);
  for (int i = tid; i < 49152; i += stride) {
    int o = i >> 7, c = i & 127;
    int f = (o >> 4) * 4 + (c >> 5);
    int lane = (o & 15) + (((c >> 3) & 3) << 4);
    Wf[f * 512 + lane * 8 + (c & 7)] = f2bf(wqkv[o * 128 + c]);
  }
  float* gs = ws + 2449408;
  if (tid < 128) gs[tid] = g[tid] * 11.313708498984761f;  // sqrt(128)
}

// ---------------- K1: rmsnorm + MFMA qkv + q-softmax + MFMA S/Z partials ----------------
// grid 1024 = 32 b * 32 groups; each block does 2 tiles of 64 px.
__global__ __launch_bounds__(256, 2) void k1_qkv(
    const float* __restrict__ x, const unsigned short* __restrict__ Wf,
    const float* __restrict__ gs, unsigned short* __restrict__ Sp,
    unsigned short* __restrict__ Zp, unsigned short* __restrict__ qbf) {
  __shared__ __align__(16) unsigned short xnf[16 * 512];   // 16 KB: B-frags of xn
  __shared__ __align__(16) unsigned short kbuf[128 * 64];  // 16 KB: exp(k), XOR-swizzled
  __shared__ __align__(16) unsigned short vbuf[128 * 64];  // 16 KB: v, XOR-swizzled
  __shared__ float ssred[256];                             // 1 KB
  const int b = blockIdx.x >> 5, grp = blockIdx.x & 31;
  const int tid = threadIdx.x;
  const int p = tid & 63, w = tid >> 6;
  const int chunk = __builtin_amdgcn_readfirstlane(w);   // wave id == head id
  const int l = p, quad = l >> 4, l16 = l & 15;

  short8 ones;                 // bf16 1.0 in every slot (B operand for Z row-sums)
#pragma unroll
  for (int j = 0; j < 8; j++) ones[j] = (short)0x3F80;

  f32x4 accS[2][2] = {};       // S partial: [d-block][e-block], head = chunk
  f32x4 accZ[2] = {};          // Z partial: [d-block] (cols replicated)

  const float* xbase = x + (size_t)b * 524288;
  float xr[32];
  {  // prologue: load tile grp*2's column (c = chunk*32+i) for pixel p
    const float* xb = xbase + grp * 128 + p;
#pragma unroll
    for (int i = 0; i < 32; i++) xr[i] = xb[(size_t)(chunk * 32 + i) * 4096];
  }

#pragma unroll 1
  for (int t = 0; t < 2; t++) {
    const int tile = grp * 2 + t;
    // phase 1: rmsnorm on prefetched xr
    float ss = 0.f;
#pragma unroll
    for (int i = 0; i < 32; i++) ss += xr[i] * xr[i];
    ssred[w * 64 + p] = ss;
    __syncthreads();  // (A) also fences prev iter's kbuf/vbuf readers
    float tot = ssred[p] + ssred[64 + p] + ssred[128 + p] + ssred[192 + p];
    float inv = 1.0f / fmaxf(sqrtf(tot), 1e-12f);
#pragma unroll
    for (int q8 = 0; q8 < 4; q8++) {
      short8 v8;
#pragma unroll
      for (int j = 0; j < 8; j++) {
        int i = q8 * 8 + j;
        v8[j] = (short)f2bf(xr[i] * gs[chunk * 32 + i] * inv);
      }
      *(short8*)&xnf[(chunk * 4 + (p >> 4)) * 512 + ((p & 15) + q8 * 16) * 8] = v8;
    }
    __syncthreads();  // (B) xnf ready

    // prefetch next tile's x under the MFMA sections (xr consumed above)
    if (t == 0) {
      const float* xb = xbase + (tile + 1) * 64 + p;
#pragma unroll
      for (int i = 0; i < 32; i++) xr[i] = xb[(size_t)(chunk * 32 + i) * 4096];
    }

    // phase 2+3: each wave does one 32-row section per s: s=0 q, s=1 k, s=2 v
    const short8* Wfv = (const short8*)Wf;
#pragma unroll
    for (int s = 0; s < 3; s++) {
      f32x4 acc[2][4] = {};
#pragma unroll
      for (int k0 = 0; k0 < 4; k0++) {
        short8 bfr[4];
#pragma unroll
        for (int n0 = 0; n0 < 4; n0++)
          bfr[n0] = *(const short8*)&xnf[(k0 * 4 + n0) * 512 + l * 8];
#pragma unroll
        for (int off = 0; off < 2; off++) {
          short8 afr = Wfv[((s * 8 + chunk * 2 + off) * 4 + k0) * 64 + l];
#pragma unroll
          for (int n0 = 0; n0 < 4; n0++)
            acc[off][n0] = __builtin_amdgcn_mfma_f32_16x16x32_bf16(afr, bfr[n0], acc[off][n0], 0, 0, 0);
        }
      }
      if (s == 0) {  // q: per-pixel softmax over d, packed 8B global stores
#pragma unroll
        for (int n0 = 0; n0 < 4; n0++) {
          float m = -1e30f;
#pragma unroll
          for (int off = 0; off < 2; off++)
#pragma unroll
            for (int r = 0; r < 4; r++) m = fmaxf(m, acc[off][n0][r]);
          m = fmaxf(m, __shfl_xor(m, 16, 64));
          m = fmaxf(m, __shfl_xor(m, 32, 64));
          float e[2][4]; float sum = 0.f;
#pragma unroll
          for (int off = 0; off < 2; off++)
#pragma unroll
            for (int r = 0; r < 4; r++) {
              e[off][r] = __expf(acc[off][n0][r] - m);
              sum += e[off][r];
            }
          sum += __shfl_xor(sum, 16, 64);
          sum += __shfl_xor(sum, 32, 64);
          float rs = 0.17677669529663687f / sum;  // dh^-0.5 / sum
          int qbase = ((b * 64 + tile) * 16 + chunk * 4 + n0) * 512;
#pragma unroll
          for (int off = 0; off < 2; off++) {
            int lane2 = l16 + ((off * 2 + (quad >> 1)) << 4);
            bf16x4 qv;
#pragma unroll
            for (int r = 0; r < 4; r++) qv[r] = (short)f2bf(e[off][r] * rs);
            *(bf16x4*)&qbf[qbase + lane2 * 8 + (quad & 1) * 4] = qv;
          }
        }
      } else if (s == 1) {  // k -> exp -> swizzled LDS (wave-private rows)
#pragma unroll
        for (int off = 0; off < 2; off++)
#pragma unroll
          for (int n0 = 0; n0 < 4; n0++)
#pragma unroll
            for (int r = 0; r < 4; r++) {
              int row = off * 16 + quad * 4 + r;
              int px = n0 * 16 + l16;
              kbuf[(chunk * 32 + row) * 64 + (px ^ ((row & 7) << 3))] = f2bf(__expf(acc[off][n0][r]));
            }
      } else {  // v -> swizzled LDS (wave-private rows)
#pragma unroll
        for (int off = 0; off < 2; off++)
#pragma unroll
          for (int n0 = 0; n0 < 4; n0++)
#pragma unroll
            for (int r = 0; r < 4; r++) {
              int row = off * 16 + quad * 4 + r;
              int px = n0 * 16 + l16;
              vbuf[(chunk * 32 + row) * 64 + (px ^ ((row & 7) << 3))] = f2bf(acc[off][n0][r]);
            }
      }
    }

    // phase 4: S/Z via MFMA over this tile's 64 px (own head's rows only,
    // same-wave RAW through LDS -> no barrier needed; (A) of next iter fences reuse)
    const unsigned short* kb = kbuf + chunk * 2048;
    const unsigned short* vb = vbuf + chunk * 2048;
#pragma unroll
    for (int kk = 0; kk < 2; kk++) {
      int cofs = (kk * 32 + quad * 8) ^ ((l16 & 7) << 3);
      short8 ak[2], av[2];
#pragma unroll
      for (int mm = 0; mm < 2; mm++) {
        ak[mm] = *(const short8*)&kb[(mm * 16 + l16) * 64 + cofs];
        av[mm] = *(const short8*)&vb[(mm * 16 + l16) * 64 + cofs];
      }
#pragma unroll
      for (int mm = 0; mm < 2; mm++) {
#pragma unroll
        for (int nn = 0; nn < 2; nn++)
          accS[mm][nn] = __builtin_amdgcn_mfma_f32_16x16x32_bf16(ak[mm], av[nn], accS[mm][nn], 0, 0, 0);
        accZ[mm] = __builtin_amdgcn_mfma_f32_16x16x32_bf16(ak[mm], ones, accZ[mm], 0, 0, 0);
      }
    }
  }

  // write bf16 partials frag-major (coalesced 8B stores, no atomics)
  unsigned short* Spb = Sp + (size_t)(b * 32 + grp) * 4096 + chunk * 1024;
#pragma unroll
  for (int mm = 0; mm < 2; mm++)
#pragma unroll
    for (int nn = 0; nn < 2; nn++) {
      bf16x4 sv;
#pragma unroll
      for (int r = 0; r < 4; r++) sv[r] = (short)f2bf(accS[mm][nn][r]);
      *(bf16x4*)&Spb[(mm * 2 + nn) * 256 + l * 4] = sv;
    }
  if (l16 == 0) {
#pragma unroll
    for (int mm = 0; mm < 2; mm++) {
      bf16x4 zv;
#pragma unroll
      for (int r = 0; r < 4; r++) zv[r] = (short)f2bf(accZ[mm][r]);
      *(bf16x4*)&Zp[(b * 32 + grp) * 128 + chunk * 32 + mm * 16 + quad * 4] = zv;
    }
  }
}

// ---------------- K2: reduce partials + context + fold w_out -> Mtf ----------------
// grid 512 = 32 b * 16 slices; each slice owns 8 context rows (one head).
__global__ __launch_bounds__(256) void k2_ctx(
    const unsigned short* __restrict__ Sp, const unsigned short* __restrict__ Zp,
    const float* __restrict__ memkv, const float* __restrict__ wout,
    unsigned short* __restrict__ Mtf) {
  __shared__ float wl[128 * 33];   // wout[:, h*32 .. +32] staged, padded
  __shared__ float Cs[8 * 32];     // context rows [hdi][e]
  __shared__ float zsh[8];
  __shared__ float zinv_s[8];
  const int b = blockIdx.x >> 4, sl = blockIdx.x & 15, tid = threadIdx.x;
  const int hd0 = sl * 8, h = hd0 >> 5;
  // stage wout column block (coalesced 128B runs)
  for (int i = tid; i < 4096; i += 256) {
    int o = i >> 5, e = i & 31;
    wl[o * 33 + e] = wout[o * 128 + h * 32 + e];
  }
  // Z reduce: tid = hdi*32 + g, shuffle within 32-lane segments
  {
    int hdi = tid >> 5, g = tid & 31;
    float zp = bf2f(Zp[(b * 32 + g) * 128 + hd0 + hdi]);
#pragma unroll
    for (int s2 = 1; s2 < 32; s2 <<= 1) zp += __shfl_xor(zp, s2, 32);
    if (g == 0) zsh[hdi] = zp;
  }
  __syncthreads();
  if (tid < 8) {
    int hd = hd0 + tid;
    float zm = 0.f;
#pragma unroll
    for (int j = 0; j < 4; j++) zm += __expf(memkv[hd * 4 + j]);
    zinv_s[tid] = 1.0f / (zsh[tid] + zm);
  }
  __syncthreads();
  // S reduce: one (hdi, e) cell per thread
  {
    int hdi = tid >> 5, e = tid & 31;
    int hd = hd0 + hdi, d = hd & 31;
    int fofs = h * 1024 + ((d >> 4) * 2 + (e >> 4)) * 256 + ((e & 15) + ((d >> 2) & 3) * 16) * 4 + (d & 3);
    const unsigned short* Spb = Sp + (size_t)b * 131072 + fofs;
    float s = 0.f;
#pragma unroll
    for (int g = 0; g < 32; g++) s += bf2f(Spb[g * 4096]);
    float sm = 0.f;
#pragma unroll
    for (int j = 0; j < 4; j++)
      sm += __expf(memkv[hd * 4 + j]) * memkv[512 + (h * 32 + e) * 4 + j];
    Cs[hdi * 32 + e] = (s + sm) * zinv_s[hdi];
  }
  __syncthreads();
  // fold wout: 4 outputs per thread
  for (int i = tid; i < 1024; i += 256) {
    int o = i & 127, hdi = i >> 7;
    float a = 0.f;
#pragma unroll
    for (int e = 0; e < 32; e++) a += wl[o * 33 + e] * Cs[hdi * 32 + e];
    int hd = hd0 + hdi;
    int f = (o >> 4) * 4 + h;
    int lane = (o & 15) + (((hd >> 3) & 3) << 4);
    Mtf[(size_t)b * 16384 + f * 512 + lane * 8 + (hd & 7)] = f2bf(a);
  }
}

// ---------------- K3: out = Mtf x q + b_out (MFMA, direct stores, 16 KB LDS) ----------------
__global__ __launch_bounds__(256) void k3_out(
    const unsigned short* __restrict__ qbf, const unsigned short* __restrict__ Mtf,
    const float* __restrict__ bout, float* __restrict__ out) {
  __shared__ __align__(16) unsigned short qf[16 * 512];   // 16 KB
  const int b = blockIdx.x >> 6, tile = blockIdx.x & 63;
  const int tid = threadIdx.x;
  const int l = tid & 63, quad = l >> 4, l16 = l & 15;
  const int chunk = __builtin_amdgcn_readfirstlane(tid >> 6);
  // prefetch Mtf A-frags first (independent of qf staging; latency overlaps)
  const short8* Mv = (const short8*)Mtf;
  short8 afr[2][4];
#pragma unroll
  for (int mm = 0; mm < 2; mm++)
#pragma unroll
    for (int k0 = 0; k0 < 4; k0++)
      afr[mm][k0] = Mv[((size_t)b * 32 + (chunk * 2 + mm) * 4 + k0) * 64 + l];
  const short8* qv = (const short8*)qbf;
  const int base = ((b * 64 + tile) * 16) * 64;  // short8 units
#pragma unroll
  for (int r = 0; r < 4; r++) {
    int cid = tid + 256 * r;
    *(short8*)&qf[cid * 8] = qv[base + cid];
  }
  __syncthreads();
  f32x4 acc[2][4] = {};
#pragma unroll
  for (int k0 = 0; k0 < 4; k0++) {
    short8 bfr[4];
#pragma unroll
    for (int n0 = 0; n0 < 4; n0++)
      bfr[n0] = *(const short8*)&qf[(k0 * 4 + n0) * 512 + l * 8];
#pragma unroll
    for (int mm = 0; mm < 2; mm++)
#pragma unroll
      for (int n0 = 0; n0 < 4; n0++)
        acc[mm][n0] = __builtin_amdgcn_mfma_f32_16x16x32_bf16(afr[mm][k0], bfr[n0], acc[mm][n0], 0, 0, 0);
  }
  // direct stores: col = px on lane (16x4B = 64B contiguous per 16-lane group)
  float* ob = out + (size_t)b * 524288 + tile * 64;
#pragma unroll
  for (int mm = 0; mm < 2; mm++)
#pragma unroll
    for (int r = 0; r < 4; r++) {
      int o = chunk * 32 + mm * 16 + quad * 4 + r;
      float bv = bout[o];
#pragma unroll
      for (int n0 = 0; n0 < 4; n0++)
        ob[(size_t)o * 4096 + n0 * 16 + l16] = acc[mm][n0][r] + bv;
    }
}

extern "C" void kernel_launch(void* const* d_in, const int* in_sizes, int n_in,
                              void* d_out, int out_size, void* d_ws, size_t ws_size,
                              hipStream_t stream) {
  const float* x     = (const float*)d_in[0];
  const float* g     = (const float*)d_in[1];
  const float* wqkv  = (const float*)d_in[2];
  const float* memkv = (const float*)d_in[3];
  const float* wout  = (const float*)d_in[4];
  const float* bout  = (const float*)d_in[5];
  float* out = (float*)d_out;
  float* ws = (float*)d_ws;
  unsigned short* Sp  = (unsigned short*)ws;
  unsigned short* Zp  = (unsigned short*)(ws + 2097152);
  unsigned short* Mtf = (unsigned short*)(ws + 2162688);
  unsigned short* Wf  = (unsigned short*)(ws + 2424832);
  float* gs  = ws + 2449408;
  unsigned short* qbf = (unsigned short*)(ws + 2449536);

  k0_init<<<128, 256, 0, stream>>>(wqkv, g, ws);
  k1_qkv<<<1024, 256, 0, stream>>>(x, Wf, gs, Sp, Zp, qbf);
  k2_ctx<<<512, 256, 0, stream>>>(Sp, Zp, memkv, wout, Mtf);
  k3_out<<<2048, 256, 0, stream>>>(qbf, Mtf, bout, out);
}

// Round 6
// 187.533 us; speedup vs baseline: 1.2827x; 1.2827x over previous
//
#include <hip/hip_runtime.h>
#include <hip/hip_bf16.h>

typedef __attribute__((ext_vector_type(8))) short short8;   // 8 bf16 (A/B frag)
typedef __attribute__((ext_vector_type(4))) short bf16x4;   // 4 bf16 (8B store)
typedef __attribute__((ext_vector_type(4))) float f32x4;    // 4 fp32 (C/D frag)

// b=32, C=128, n=4096, heads=4, dh=32. All I/O fp32; MFMA bf16, fp32 accum.
// K1: round-2's proven 68us kernel VERBATIM (grid 512 = 32 b x 16 groups x 4 tiles,
// full-width swizzled kbuf/vbuf, 3-section loop, xr prefetch, launch_bounds(256,2)).
// Re-gridding experiments (r3/r4/r5) all regressed; config is settled.
// K2: 512-block parallel reduce (16 groups).
// K3: NO LDS, NO barrier — each wave loads its 16 B-frags directly from
// frag-major qbf (redundant wave reads hit L1/L2); pure load->MFMA->store.
//
// ws (float units):
//   Sp  bf16 frag-major [32][16][4096] @ 0
//   Zp  bf16 [32][16][128]  @ 2097152
//   Mtf bf16 frag-major     @ 2162688
//   Wf  bf16 frag-major     @ 2424832
//   gs  [128]               @ 2449408
//   qbf bf16 frag-major     @ 2449536

__device__ __forceinline__ unsigned short f2bf(float f) {  // RNE, finite inputs
  unsigned u = __float_as_uint(f);
  u += 0x7fff + ((u >> 16) & 1);
  return (unsigned short)(u >> 16);
}
__device__ __forceinline__ float bf2f(unsigned short s) {
  return __uint_as_float(((unsigned)s) << 16);
}

// ---------------- K0: pack Wf frag-major, gs ----------------
__global__ void k0_init(const float* __restrict__ wqkv, const float* __restrict__ g,
                        float* __restrict__ ws) {
  int tid = blockIdx.x * blockDim.x + threadIdx.x;
  int stride = gridDim.x * blockDim.x;
  unsigned short* Wf = (unsigned short*)(ws + 2424832);
  for (int i = tid; i < 49152; i += stride) {
    int o = i >> 7, c = i & 127;
    int f = (o >> 4) * 4 + (c >> 5);
    int lane = (o & 15) + (((c >> 3) & 3) << 4);
    Wf[f * 512 + lane * 8 + (c & 7)] = f2bf(wqkv[o * 128 + c]);
  }
  float* gs = ws + 2449408;
  if (tid < 128) gs[tid] = g[tid] * 11.313708498984761f;  // sqrt(128)
}

// ---------------- K1: rmsnorm + MFMA qkv + q-softmax + MFMA S/Z partials ----------------
// grid 512 = 32 b * 16 groups; each block does 4 tiles of 64 px.
__global__ __launch_bounds__(256, 2) void k1_qkv(
    const float* __restrict__ x, const unsigned short* __restrict__ Wf,
    const float* __restrict__ gs, unsigned short* __restrict__ Sp,
    unsigned short* __restrict__ Zp, unsigned short* __restrict__ qbf) {
  __shared__ __align__(16) unsigned short xnf[16 * 512];   // 16 KB: B-frags of xn
  __shared__ __align__(16) unsigned short kbuf[128 * 64];  // 16 KB: exp(k), XOR-swizzled
  __shared__ __align__(16) unsigned short vbuf[128 * 64];  // 16 KB: v, XOR-swizzled
  __shared__ float ssred[256];                             // 1 KB
  const int b = blockIdx.x >> 4, grp = blockIdx.x & 15;
  const int tid = threadIdx.x;
  const int p = tid & 63, w = tid >> 6;
  const int chunk = __builtin_amdgcn_readfirstlane(w);   // wave id == head id
  const int l = p, quad = l >> 4, l16 = l & 15;

  short8 ones;                 // bf16 1.0 in every slot (B operand for Z row-sums)
#pragma unroll
  for (int j = 0; j < 8; j++) ones[j] = (short)0x3F80;

  f32x4 accS[2][2] = {};       // S partial: [d-block][e-block], head = chunk
  f32x4 accZ[2] = {};          // Z partial: [d-block] (cols replicated)

  const float* xbase = x + (size_t)b * 524288;
  float xr[32];
  {  // prologue: load tile grp*4's column (c = chunk*32+i) for pixel p
    const float* xb = xbase + grp * 256 + p;
#pragma unroll
    for (int i = 0; i < 32; i++) xr[i] = xb[(size_t)(chunk * 32 + i) * 4096];
  }

#pragma unroll 1
  for (int t = 0; t < 4; t++) {
    const int tile = grp * 4 + t;
    // phase 1: rmsnorm on prefetched xr
    float ss = 0.f;
#pragma unroll
    for (int i = 0; i < 32; i++) ss += xr[i] * xr[i];
    ssred[w * 64 + p] = ss;
    __syncthreads();  // (A) also fences prev iter's kbuf/vbuf readers
    float tot = ssred[p] + ssred[64 + p] + ssred[128 + p] + ssred[192 + p];
    float inv = 1.0f / fmaxf(sqrtf(tot), 1e-12f);
#pragma unroll
    for (int q8 = 0; q8 < 4; q8++) {
      short8 v8;
#pragma unroll
      for (int j = 0; j < 8; j++) {
        int i = q8 * 8 + j;
        v8[j] = (short)f2bf(xr[i] * gs[chunk * 32 + i] * inv);
      }
      *(short8*)&xnf[(chunk * 4 + (p >> 4)) * 512 + ((p & 15) + q8 * 16) * 8] = v8;
    }
    __syncthreads();  // (B) xnf ready

    // prefetch next tile's x under the MFMA sections (xr consumed above)
    if (t < 3) {
      const float* xb = xbase + (tile + 1) * 64 + p;
#pragma unroll
      for (int i = 0; i < 32; i++) xr[i] = xb[(size_t)(chunk * 32 + i) * 4096];
    }

    // phase 2+3: each wave does one 32-row section per s: s=0 q, s=1 k, s=2 v
    const short8* Wfv = (const short8*)Wf;
#pragma unroll
    for (int s = 0; s < 3; s++) {
      f32x4 acc[2][4] = {};
#pragma unroll
      for (int k0 = 0; k0 < 4; k0++) {
        short8 bfr[4];
#pragma unroll
        for (int n0 = 0; n0 < 4; n0++)
          bfr[n0] = *(const short8*)&xnf[(k0 * 4 + n0) * 512 + l * 8];
#pragma unroll
        for (int off = 0; off < 2; off++) {
          short8 afr = Wfv[((s * 8 + chunk * 2 + off) * 4 + k0) * 64 + l];
#pragma unroll
          for (int n0 = 0; n0 < 4; n0++)
            acc[off][n0] = __builtin_amdgcn_mfma_f32_16x16x32_bf16(afr, bfr[n0], acc[off][n0], 0, 0, 0);
        }
      }
      if (s == 0) {  // q: per-pixel softmax over d, packed 8B global stores
#pragma unroll
        for (int n0 = 0; n0 < 4; n0++) {
          float m = -1e30f;
#pragma unroll
          for (int off = 0; off < 2; off++)
#pragma unroll
            for (int r = 0; r < 4; r++) m = fmaxf(m, acc[off][n0][r]);
          m = fmaxf(m, __shfl_xor(m, 16, 64));
          m = fmaxf(m, __shfl_xor(m, 32, 64));
          float e[2][4]; float sum = 0.f;
#pragma unroll
          for (int off = 0; off < 2; off++)
#pragma unroll
            for (int r = 0; r < 4; r++) {
              e[off][r] = __expf(acc[off][n0][r] - m);
              sum += e[off][r];
            }
          sum += __shfl_xor(sum, 16, 64);
          sum += __shfl_xor(sum, 32, 64);
          float rs = 0.17677669529663687f / sum;  // dh^-0.5 / sum
          int qbase = ((b * 64 + tile) * 16 + chunk * 4 + n0) * 512;
#pragma unroll
          for (int off = 0; off < 2; off++) {
            int lane2 = l16 + ((off * 2 + (quad >> 1)) << 4);
            bf16x4 qv;
#pragma unroll
            for (int r = 0; r < 4; r++) qv[r] = (short)f2bf(e[off][r] * rs);
            *(bf16x4*)&qbf[qbase + lane2 * 8 + (quad & 1) * 4] = qv;
          }
        }
      } else if (s == 1) {  // k -> exp -> swizzled LDS (wave-private rows)
#pragma unroll
        for (int off = 0; off < 2; off++)
#pragma unroll
          for (int n0 = 0; n0 < 4; n0++)
#pragma unroll
            for (int r = 0; r < 4; r++) {
              int row = off * 16 + quad * 4 + r;
              int px = n0 * 16 + l16;
              kbuf[(chunk * 32 + row) * 64 + (px ^ ((row & 7) << 3))] = f2bf(__expf(acc[off][n0][r]));
            }
      } else {  // v -> swizzled LDS (wave-private rows)
#pragma unroll
        for (int off = 0; off < 2; off++)
#pragma unroll
          for (int n0 = 0; n0 < 4; n0++)
#pragma unroll
            for (int r = 0; r < 4; r++) {
              int row = off * 16 + quad * 4 + r;
              int px = n0 * 16 + l16;
              vbuf[(chunk * 32 + row) * 64 + (px ^ ((row & 7) << 3))] = f2bf(acc[off][n0][r]);
            }
      }
    }

    // phase 4: S/Z via MFMA over this tile's 64 px (own head's rows only,
    // same-wave RAW through LDS -> no barrier needed; (A) of next iter fences reuse)
    const unsigned short* kb = kbuf + chunk * 2048;
    const unsigned short* vb = vbuf + chunk * 2048;
#pragma unroll
    for (int kk = 0; kk < 2; kk++) {
      int cofs = (kk * 32 + quad * 8) ^ ((l16 & 7) << 3);
      short8 ak[2], av[2];
#pragma unroll
      for (int mm = 0; mm < 2; mm++) {
        ak[mm] = *(const short8*)&kb[(mm * 16 + l16) * 64 + cofs];
        av[mm] = *(const short8*)&vb[(mm * 16 + l16) * 64 + cofs];
      }
#pragma unroll
      for (int mm = 0; mm < 2; mm++) {
#pragma unroll
        for (int nn = 0; nn < 2; nn++)
          accS[mm][nn] = __builtin_amdgcn_mfma_f32_16x16x32_bf16(ak[mm], av[nn], accS[mm][nn], 0, 0, 0);
        accZ[mm] = __builtin_amdgcn_mfma_f32_16x16x32_bf16(ak[mm], ones, accZ[mm], 0, 0, 0);
      }
    }
  }

  // write bf16 partials frag-major (coalesced 8B stores, no atomics)
  unsigned short* Spb = Sp + (size_t)(b * 16 + grp) * 4096 + chunk * 1024;
#pragma unroll
  for (int mm = 0; mm < 2; mm++)
#pragma unroll
    for (int nn = 0; nn < 2; nn++) {
      bf16x4 sv;
#pragma unroll
      for (int r = 0; r < 4; r++) sv[r] = (short)f2bf(accS[mm][nn][r]);
      *(bf16x4*)&Spb[(mm * 2 + nn) * 256 + l * 4] = sv;
    }
  if (l16 == 0) {
#pragma unroll
    for (int mm = 0; mm < 2; mm++) {
      bf16x4 zv;
#pragma unroll
      for (int r = 0; r < 4; r++) zv[r] = (short)f2bf(accZ[mm][r]);
      *(bf16x4*)&Zp[(b * 16 + grp) * 128 + chunk * 32 + mm * 16 + quad * 4] = zv;
    }
  }
}

// ---------------- K2: reduce partials + context + fold w_out -> Mtf ----------------
// grid 512 = 32 b * 16 slices; each slice owns 8 context rows (one head).
__global__ __launch_bounds__(256) void k2_ctx(
    const unsigned short* __restrict__ Sp, const unsigned short* __restrict__ Zp,
    const float* __restrict__ memkv, const float* __restrict__ wout,
    unsigned short* __restrict__ Mtf) {
  __shared__ float wl[128 * 33];   // wout[:, h*32 .. +32] staged, padded
  __shared__ float Cs[8 * 32];     // context rows [hdi][e]
  __shared__ float zsh[8];
  __shared__ float zinv_s[8];
  const int b = blockIdx.x >> 4, sl = blockIdx.x & 15, tid = threadIdx.x;
  const int hd0 = sl * 8, h = hd0 >> 5;
  // stage wout column block (coalesced 128B runs)
  for (int i = tid; i < 4096; i += 256) {
    int o = i >> 5, e = i & 31;
    wl[o * 33 + e] = wout[o * 128 + h * 32 + e];
  }
  // Z reduce: tid = hdi*32 + g (g<16 used), shuffle within 16-lane segments
  {
    int hdi = tid >> 5, g = tid & 31;
    float zp = (g < 16) ? bf2f(Zp[(b * 16 + g) * 128 + hd0 + hdi]) : 0.f;
#pragma unroll
    for (int s2 = 1; s2 < 32; s2 <<= 1) zp += __shfl_xor(zp, s2, 32);
    if (g == 0) zsh[hdi] = zp;
  }
  __syncthreads();
  if (tid < 8) {
    int hd = hd0 + tid;
    float zm = 0.f;
#pragma unroll
    for (int j = 0; j < 4; j++) zm += __expf(memkv[hd * 4 + j]);
    zinv_s[tid] = 1.0f / (zsh[tid] + zm);
  }
  __syncthreads();
  // S reduce: one (hdi, e) cell per thread
  {
    int hdi = tid >> 5, e = tid & 31;
    int hd = hd0 + hdi, d = hd & 31;
    int fofs = h * 1024 + ((d >> 4) * 2 + (e >> 4)) * 256 + ((e & 15) + ((d >> 2) & 3) * 16) * 4 + (d & 3);
    const unsigned short* Spb = Sp + (size_t)b * 65536 + fofs;
    float s = 0.f;
#pragma unroll
    for (int g = 0; g < 16; g++) s += bf2f(Spb[g * 4096]);
    float sm = 0.f;
#pragma unroll
    for (int j = 0; j < 4; j++)
      sm += __expf(memkv[hd * 4 + j]) * memkv[512 + (h * 32 + e) * 4 + j];
    Cs[hdi * 32 + e] = (s + sm) * zinv_s[hdi];
  }
  __syncthreads();
  // fold wout: 4 outputs per thread
  for (int i = tid; i < 1024; i += 256) {
    int o = i & 127, hdi = i >> 7;
    float a = 0.f;
#pragma unroll
    for (int e = 0; e < 32; e++) a += wl[o * 33 + e] * Cs[hdi * 32 + e];
    int hd = hd0 + hdi;
    int f = (o >> 4) * 4 + h;
    int lane = (o & 15) + (((hd >> 3) & 3) << 4);
    Mtf[(size_t)b * 16384 + f * 512 + lane * 8 + (hd & 7)] = f2bf(a);
  }
}

// ---------------- K3: out = Mtf x q + b_out (MFMA, NO LDS, NO barrier) ----------------
// grid 2048 = 32 b * 64 tiles. Each wave loads its 16 B-frags directly from
// frag-major qbf (other waves' duplicate reads hit L1/L2); fire-and-forget.
__global__ __launch_bounds__(256) void k3_out(
    const unsigned short* __restrict__ qbf, const unsigned short* __restrict__ Mtf,
    const float* __restrict__ bout, float* __restrict__ out) {
  const int b = blockIdx.x >> 6, tile = blockIdx.x & 63;
  const int tid = threadIdx.x;
  const int l = tid & 63, quad = l >> 4, l16 = l & 15;
  const int chunk = __builtin_amdgcn_readfirstlane(tid >> 6);
  const short8* Mv = (const short8*)Mtf;
  const short8* qv = (const short8*)qbf + (size_t)(b * 64 + tile) * 1024;
  short8 afr[2][4];
#pragma unroll
  for (int mm = 0; mm < 2; mm++)
#pragma unroll
    for (int k0 = 0; k0 < 4; k0++)
      afr[mm][k0] = Mv[((size_t)b * 32 + (chunk * 2 + mm) * 4 + k0) * 64 + l];
  f32x4 acc[2][4] = {};
#pragma unroll
  for (int hh = 0; hh < 2; hh++) {   // frag halves: k0 = 2hh, 2hh+1
    short8 bfr[8];
#pragma unroll
    for (int j = 0; j < 8; j++) bfr[j] = qv[(hh * 8 + j) * 64 + l];
#pragma unroll
    for (int kk = 0; kk < 2; kk++) {
      int k0 = hh * 2 + kk;
#pragma unroll
      for (int mm = 0; mm < 2; mm++)
#pragma unroll
        for (int n0 = 0; n0 < 4; n0++)
          acc[mm][n0] = __builtin_amdgcn_mfma_f32_16x16x32_bf16(afr[mm][k0], bfr[kk * 4 + n0], acc[mm][n0], 0, 0, 0);
    }
  }
  // direct stores: col = px on lane (16x4B = 64B contiguous per 16-lane group)
  float* ob = out + (size_t)b * 524288 + tile * 64;
#pragma unroll
  for (int mm = 0; mm < 2; mm++)
#pragma unroll
    for (int r = 0; r < 4; r++) {
      int o = chunk * 32 + mm * 16 + quad * 4 + r;
      float bv = bout[o];
#pragma unroll
      for (int n0 = 0; n0 < 4; n0++)
        ob[(size_t)o * 4096 + n0 * 16 + l16] = acc[mm][n0][r] + bv;
    }
}

extern "C" void kernel_launch(void* const* d_in, const int* in_sizes, int n_in,
                              void* d_out, int out_size, void* d_ws, size_t ws_size,
                              hipStream_t stream) {
  const float* x     = (const float*)d_in[0];
  const float* g     = (const float*)d_in[1];
  const float* wqkv  = (const float*)d_in[2];
  const float* memkv = (const float*)d_in[3];
  const float* wout  = (const float*)d_in[4];
  const float* bout  = (const float*)d_in[5];
  float* out = (float*)d_out;
  float* ws = (float*)d_ws;
  unsigned short* Sp  = (unsigned short*)ws;
  unsigned short* Zp  = (unsigned short*)(ws + 2097152);
  unsigned short* Mtf = (unsigned short*)(ws + 2162688);
  unsigned short* Wf  = (unsigned short*)(ws + 2424832);
  float* gs  = ws + 2449408;
  unsigned short* qbf = (unsigned short*)(ws + 2449536);

  k0_init<<<128, 256, 0, stream>>>(wqkv, g, ws);
  k1_qkv<<<512, 256, 0, stream>>>(x, Wf, gs, Sp, Zp, qbf);
  k2_ctx<<<512, 256, 0, stream>>>(Sp, Zp, memkv, wout, Mtf);
  k3_out<<<2048, 256, 0, stream>>>(qbf, Mtf, bout, out);
}